// Round 2
// baseline (202.489 us; speedup 1.0000x reference)
//
#include <hip/hip_runtime.h>

// Problem: BATCH=256, GRIDS=16384, TYPES=8
//   p = pred_hz[:, :, 0]          (needed floats at 32B stride -> every 64B
//                                  line of the 128MiB array must be fetched)
//   ll = sum(target ? log(p) : log(1-p));  out = -ll/256  (scalar f32)
//
// HBM floor: 128 MiB pred + 16 MiB mask = 144 MiB  ->  ~21 us @ 6.7 TB/s.
//
// R1 lesson: per-THREAD-contiguous chunking put lanes 2048B apart inside one
// load instruction (64 lines/instr, 4B used each) -> 0.75 TB/s. Fix: lanes
// consecutive in element index; lane i loads the float4 at byte e*32 (16B at
// 32B stride) -> wave spans one contiguous 2KiB region, 32 line-txns/instr,
// all fetched lines are mandatory traffic.

#define NLL_ELEMS (256 * 16384)   // 4,194,304 element groups
#define NLL_BLOCK 256
#define NLL_UNROLL 8
#define NLL_GRID (NLL_ELEMS / (NLL_BLOCK * NLL_UNROLL))   // 2048 blocks exactly

__global__ __launch_bounds__(NLL_BLOCK) void nll_partial_kernel(
    const float4* __restrict__ pred4,  // pred as float4[]; group e -> index 2e, use .x
    const int*    __restrict__ mask,   // [ELEMS] int32 (bool promoted)
    float*        __restrict__ partial)
{
    const int t = threadIdx.x;
    const int eblock = blockIdx.x * (NLL_BLOCK * NLL_UNROLL);

    float s = 0.0f;
#pragma unroll
    for (int j = 0; j < NLL_UNROLL; ++j) {
        const int e = eblock + j * NLL_BLOCK + t;   // lanes consecutive in e
        const float4 v = pred4[(long long)e * 2];    // 16B load, 32B stride
        const int   m = mask[e];                     // dense coalesced dword
        const float p = v.x;
        s += __logf(m ? p : (1.0f - p));
    }

    // Wave(64) shuffle reduction, then 4 waves via LDS.
#pragma unroll
    for (int off = 32; off > 0; off >>= 1)
        s += __shfl_down(s, off, 64);

    __shared__ float lds[NLL_BLOCK / 64];
    const int lane = t & 63;
    const int wv   = t >> 6;
    if (lane == 0) lds[wv] = s;
    __syncthreads();
    if (t == 0)
        partial[blockIdx.x] = lds[0] + lds[1] + lds[2] + lds[3];
}

__global__ __launch_bounds__(256) void nll_final_kernel(
    const float* __restrict__ partial,  // [NLL_GRID] = 2048
    float*       __restrict__ out)
{
    float s = 0.0f;
    const float4* p4 = (const float4*)partial;
#pragma unroll
    for (int k = 0; k < 2; ++k) {
        float4 v = p4[threadIdx.x * 2 + k];
        s += v.x + v.y + v.z + v.w;
    }
#pragma unroll
    for (int off = 32; off > 0; off >>= 1)
        s += __shfl_down(s, off, 64);

    __shared__ float lds[4];
    const int lane = threadIdx.x & 63;
    const int wv   = threadIdx.x >> 6;
    if (lane == 0) lds[wv] = s;
    __syncthreads();
    if (threadIdx.x == 0) {
        float total = lds[0] + lds[1] + lds[2] + lds[3];
        out[0] = -total * (1.0f / 256.0f);   // -ll / batch
    }
}

extern "C" void kernel_launch(void* const* d_in, const int* in_sizes, int n_in,
                              void* d_out, int out_size, void* d_ws, size_t ws_size,
                              hipStream_t stream)
{
    const float4* pred4 = (const float4*)d_in[0];
    const int*    mask  = (const int*)d_in[1];
    float* partial = (float*)d_ws;    // 2048 * 4B = 8 KiB scratch
    float* out = (float*)d_out;

    nll_partial_kernel<<<NLL_GRID, NLL_BLOCK, 0, stream>>>(pred4, mask, partial);
    nll_final_kernel<<<1, 256, 0, stream>>>(partial, out);
}

// Round 5
// 186.929 us; speedup vs baseline: 1.0832x; 1.0832x over previous
//
#include <hip/hip_runtime.h>

// Problem: BATCH=256, GRIDS=16384, TYPES=8
//   p = pred_hz[:, :, 0];  ll = sum(m ? log p : log(1-p));  out = -ll/256.
//
// Traffic floor: needed floats at 32B stride -> every 64B line of the
// 128MiB pred array is mandatory; + 16MiB int32 mask = 144 MiB. Inputs are
// L3-resident (256MiB Infinity Cache, refreshed by the harness's restore),
// so the kernel runs at cache speed (~10-25us incl. launch).
//
// R1 vs R2: scattered vs coalesced loads -> identical dur_us (~201) =>
// dur_us is dominated by per-iteration harness reset (536MB poison fill
// at 77us measured + ~45us input restore + overhead), not the kernel.
// R4: single-kernel last-block-done (atomic ticket) was caught by the
// harness tripwire with a nondeterministic wrong value -> reverted to the
// proven deterministic two-kernel reduction. Fusion upside was ~5us of 200;
// not worth the cross-XCD visibility risk.

#define NLL_ELEMS (256 * 16384)   // 4,194,304 element groups
#define NLL_BLOCK 256
#define NLL_UNROLL 8
#define NLL_GRID (NLL_ELEMS / (NLL_BLOCK * NLL_UNROLL))   // 2048 blocks exactly

__global__ __launch_bounds__(NLL_BLOCK) void nll_partial_kernel(
    const float* __restrict__ pred,    // group e -> float index e*8
    const int*   __restrict__ mask,    // [ELEMS] int32 (bool promoted)
    float*       __restrict__ partial) // [NLL_GRID]
{
    const int t = threadIdx.x;
    const int eblock = blockIdx.x * (NLL_BLOCK * NLL_UNROLL);

    float s = 0.0f;
#pragma unroll
    for (int j = 0; j < NLL_UNROLL; ++j) {
        const int e = eblock + j * NLL_BLOCK + t;   // lanes consecutive in e
        const float p = __builtin_nontemporal_load(&pred[(long long)e * 8]);
        const int   m = __builtin_nontemporal_load(&mask[e]);
        s += __logf(m ? p : (1.0f - p));
    }

    // Wave(64) shuffle reduction, then 4 waves via LDS.
#pragma unroll
    for (int off = 32; off > 0; off >>= 1)
        s += __shfl_down(s, off, 64);

    __shared__ float lds[NLL_BLOCK / 64];
    const int lane = t & 63;
    const int wv   = t >> 6;
    if (lane == 0) lds[wv] = s;
    __syncthreads();
    if (t == 0)
        partial[blockIdx.x] = lds[0] + lds[1] + lds[2] + lds[3];
}

__global__ __launch_bounds__(256) void nll_final_kernel(
    const float* __restrict__ partial,  // [NLL_GRID] = 2048
    float*       __restrict__ out)
{
    float s = 0.0f;
#pragma unroll
    for (int k = 0; k < NLL_GRID / 256; ++k)
        s += partial[k * 256 + threadIdx.x];
#pragma unroll
    for (int off = 32; off > 0; off >>= 1)
        s += __shfl_down(s, off, 64);

    __shared__ float lds[4];
    const int lane = threadIdx.x & 63;
    const int wv   = threadIdx.x >> 6;
    if (lane == 0) lds[wv] = s;
    __syncthreads();
    if (threadIdx.x == 0) {
        float total = lds[0] + lds[1] + lds[2] + lds[3];
        out[0] = -total * (1.0f / 256.0f);   // -ll / batch
    }
}

extern "C" void kernel_launch(void* const* d_in, const int* in_sizes, int n_in,
                              void* d_out, int out_size, void* d_ws, size_t ws_size,
                              hipStream_t stream)
{
    const float* pred = (const float*)d_in[0];
    const int*   mask = (const int*)d_in[1];
    float* partial = (float*)d_ws;    // 2048 * 4B = 8 KiB scratch
    float* out = (float*)d_out;

    nll_partial_kernel<<<NLL_GRID, NLL_BLOCK, 0, stream>>>(pred, mask, partial);
    nll_final_kernel<<<1, 256, 0, stream>>>(partial, out);
}